// Round 17
// baseline (273.596 us; speedup 1.0000x reference)
//
#include <hip/hip_runtime.h>

typedef _Float16 half8_t __attribute__((ext_vector_type(8)));
typedef _Float16 half4_t __attribute__((ext_vector_type(4)));
typedef float    float4_t __attribute__((ext_vector_type(4)));

// ---------------- ws layout (f16 elements unless noted) ----------------
// [0, 18432)        qkF   frag-order q,k weights
// [18432, 27648)    vB    frag-order v-weights
// [27648, 36864)    woutB frag-order Wout (kt-pairs)
// [36864 f16 = 73728 B, 77824 B)  biasT f32 [4][16][16]
#define VB_OFF 18432
#define WOUTB_OFF 27648
#define BIAST_OFF_B 73728

__global__ void prep_kernel(const float* __restrict__ Wqkv,
                            const float* __restrict__ Wout,
                            const float* __restrict__ pos,
                            _Float16* __restrict__ wsh,
                            float* __restrict__ biasT) {
  int idx = blockIdx.x * 256 + threadIdx.x;
  if (idx < 18432) {
    int j = idx & 7, lane = (idx >> 3) & 63, fk = idx >> 9;   // fk in [0,36)
    int f = fk / 3, kt = fk % 3;
    int l15 = lane & 15, g = lane >> 4;
    int k = kt * 32 + g * 8 + j;
    int fo = f * 16 + l15;
    wsh[idx] = (_Float16)Wqkv[k * 288 + fo];
  } else if (idx < 27648) {
    int t = idx - VB_OFF;
    int j = t & 7, lane = (t >> 3) & 63, fk = t >> 9;         // fk in [0,18)
    int f6 = fk / 3, kt = fk % 3;
    int l15 = lane & 15, g = lane >> 4;
    int k = kt * 32 + g * 8 + j;
    int fo = 192 + f6 * 16 + l15;
    wsh[idx] = (_Float16)Wqkv[k * 288 + fo];
  } else if (idx < 36864) {
    int t = idx - WOUTB_OFF;
    int s = t & 7, lane = (t >> 3) & 63, fk = t >> 9;         // fk in [0,18)
    int mt = fk / 3, kp = fk % 3;
    int l15 = lane & 15, g = lane >> 4;
    int kt = kp * 2 + (s >> 2), j = s & 3;
    int k = kt * 16 + g * 4 + j;
    int fo = mt * 16 + l15;
    wsh[idx] = (_Float16)Wout[k * 96 + fo];
  } else if (idx < 36864 + 1024) {
    int t = idx - 36864;
    int m = t >> 8, j = (t >> 4) & 15, i = t & 15;            // [j][i] = bias[i][j]
    int xi = i >> 2, yi = i & 3, xj = j >> 2, yj = j & 3;
    float v = pos[(xj - xi + 3) * 7 + (yj - yi + 3)];         // key minus query
    if ((m & 1) && ((i >= 8) != (j >= 8))) v -= 1e9f;
    if ((m & 2) && ((yi >= 2) != (yj >= 2))) v -= 1e9f;
    biasT[t] = v;
  }
}

static __device__ __forceinline__ half4_t pack4(float4_t a) {
  half4_t h;
  h[0] = (_Float16)a[0]; h[1] = (_Float16)a[1];
  h[2] = (_Float16)a[2]; h[3] = (_Float16)a[3];
  return h;
}

static __device__ __forceinline__ void gload_lds16(const void* g, void* l) {
  __builtin_amdgcn_global_load_lds(
      (const __attribute__((address_space(1))) unsigned int*)g,
      (__attribute__((address_space(3))) unsigned int*)l, 16, 0, 0);
}

// issue x loads + bias loads for a 2-window set (gwin = first window flat idx)
static __device__ __forceinline__ void load_set(
    const float* __restrict__ x, const float* __restrict__ biasT,
    int gwin, int ty, int tx, int g, int l15,
    int* pp, int* qq, float* bb0, float* bb1, float* bb2, float* bb3,
    float4_t xa[2][3], float4_t xb[2][3]) {
  const int batch = gwin / 784;
  const int wid0  = gwin % 784;
#pragma unroll
  for (int w = 0; w < 2; ++w) {
    int wid = wid0 + w;
    int wrow = wid / 28, wcol = wid % 28;
    int p = wrow * 4 + ty + 2; if (p >= 112) p -= 112;
    int q = wcol * 4 + tx + 2; if (q >= 112) q -= 112;
    pp[w] = p; qq[w] = q;
    const float* xr = x + (((size_t)batch * 112 + p) * 112 + q) * 96 + g * 8;
#pragma unroll
    for (int kt = 0; kt < 3; ++kt) {
      xa[w][kt] = *(const float4_t*)(xr + kt * 32);
      xb[w][kt] = *(const float4_t*)(xr + kt * 32 + 4);
    }
    int var = (wrow == 27 ? 1 : 0) + (wcol == 27 ? 2 : 0);
    const float* bt = biasT + var * 256 + g * 64 + l15;   // [var][j=4g+r][i=l15]
    bb0[w] = bt[0]; bb1[w] = bt[16]; bb2[w] = bt[32]; bb3[w] = bt[48];
  }
}

static __device__ __forceinline__ void conv_set(const float4_t xa[2][3],
                                                const float4_t xb[2][3],
                                                half8_t xf[2][3]) {
#pragma unroll
  for (int w = 0; w < 2; ++w)
#pragma unroll
    for (int kt = 0; kt < 3; ++kt) {
      half8_t h;
      h[0] = (_Float16)xa[w][kt][0]; h[1] = (_Float16)xa[w][kt][1];
      h[2] = (_Float16)xa[w][kt][2]; h[3] = (_Float16)xa[w][kt][3];
      h[4] = (_Float16)xb[w][kt][0]; h[5] = (_Float16)xb[w][kt][1];
      h[6] = (_Float16)xb[w][kt][2]; h[7] = (_Float16)xb[w][kt][3];
      xf[w][kt] = h;
    }
}

// GEMM1 (qk + v) + attention for a 2-window set -> ao[2][6]  (r12 dataflow)
static __device__ __forceinline__ void attn_pair(
    const half8_t xf[2][3], const float* bb0, const float* bb1,
    const float* bb2, const float* bb3,
    const _Float16* qkF, const _Float16* vF, int lane, half4_t ao[2][6]) {
  const float scale = 0.17677669529663687f;  // 32^-0.5
  half4_t qk16[2][12];
#pragma unroll
  for (int f = 0; f < 12; ++f) {
    half8_t w0 = *(const half8_t*)&qkF[((f * 3 + 0) * 64 + lane) * 8];
    half8_t w1 = *(const half8_t*)&qkF[((f * 3 + 1) * 64 + lane) * 8];
    half8_t w2 = *(const half8_t*)&qkF[((f * 3 + 2) * 64 + lane) * 8];
    float4_t a0 = {0.f, 0.f, 0.f, 0.f};
    float4_t a1 = {0.f, 0.f, 0.f, 0.f};
    a0 = __builtin_amdgcn_mfma_f32_16x16x32_f16(w0, xf[0][0], a0, 0, 0, 0);
    a1 = __builtin_amdgcn_mfma_f32_16x16x32_f16(w0, xf[1][0], a1, 0, 0, 0);
    a0 = __builtin_amdgcn_mfma_f32_16x16x32_f16(w1, xf[0][1], a0, 0, 0, 0);
    a1 = __builtin_amdgcn_mfma_f32_16x16x32_f16(w1, xf[1][1], a1, 0, 0, 0);
    a0 = __builtin_amdgcn_mfma_f32_16x16x32_f16(w2, xf[0][2], a0, 0, 0, 0);
    a1 = __builtin_amdgcn_mfma_f32_16x16x32_f16(w2, xf[1][2], a1, 0, 0, 0);
    qk16[0][f] = pack4(a0);
    qk16[1][f] = pack4(a1);
  }
  half4_t vt16[2][6];
#pragma unroll
  for (int f6 = 0; f6 < 6; ++f6) {
    half8_t vb0 = *(const half8_t*)&vF[((f6 * 3 + 0) * 64 + lane) * 8];
    half8_t vb1 = *(const half8_t*)&vF[((f6 * 3 + 1) * 64 + lane) * 8];
    half8_t vb2 = *(const half8_t*)&vF[((f6 * 3 + 2) * 64 + lane) * 8];
    float4_t a0 = {0.f, 0.f, 0.f, 0.f};
    float4_t a1 = {0.f, 0.f, 0.f, 0.f};
    a0 = __builtin_amdgcn_mfma_f32_16x16x32_f16(xf[0][0], vb0, a0, 0, 0, 0);
    a1 = __builtin_amdgcn_mfma_f32_16x16x32_f16(xf[1][0], vb0, a1, 0, 0, 0);
    a0 = __builtin_amdgcn_mfma_f32_16x16x32_f16(xf[0][1], vb1, a0, 0, 0, 0);
    a1 = __builtin_amdgcn_mfma_f32_16x16x32_f16(xf[1][1], vb1, a1, 0, 0, 0);
    a0 = __builtin_amdgcn_mfma_f32_16x16x32_f16(xf[0][2], vb2, a0, 0, 0, 0);
    a1 = __builtin_amdgcn_mfma_f32_16x16x32_f16(xf[1][2], vb2, a1, 0, 0, 0);
    vt16[0][f6] = pack4(a0);
    vt16[1][f6] = pack4(a1);
  }
  float ps[2][3][4], ss[2][3];
#pragma unroll
  for (int h = 0; h < 3; ++h)
#pragma unroll
    for (int w = 0; w < 2; ++w) {
      float4_t dd = {0.f, 0.f, 0.f, 0.f};
      dd = __builtin_amdgcn_mfma_f32_16x16x16f16(qk16[w][6 + 2 * h], qk16[w][2 * h],     dd, 0, 0, 0);
      dd = __builtin_amdgcn_mfma_f32_16x16x16f16(qk16[w][7 + 2 * h], qk16[w][2 * h + 1], dd, 0, 0, 0);
      ps[w][h][0] = __expf(fmaf(dd[0], scale, bb0[w]));
      ps[w][h][1] = __expf(fmaf(dd[1], scale, bb1[w]));
      ps[w][h][2] = __expf(fmaf(dd[2], scale, bb2[w]));
      ps[w][h][3] = __expf(fmaf(dd[3], scale, bb3[w]));
      ss[w][h] = (ps[w][h][0] + ps[w][h][1]) + (ps[w][h][2] + ps[w][h][3]);
    }
#pragma unroll
  for (int w = 0; w < 2; ++w)
#pragma unroll
    for (int h = 0; h < 3; ++h)
      ss[w][h] += __shfl_xor(ss[w][h], 16, 64);
#pragma unroll
  for (int w = 0; w < 2; ++w)
#pragma unroll
    for (int h = 0; h < 3; ++h)
      ss[w][h] += __shfl_xor(ss[w][h], 32, 64);
#pragma unroll
  for (int h = 0; h < 3; ++h)
#pragma unroll
    for (int w = 0; w < 2; ++w) {
      float r = __builtin_amdgcn_rcpf(ss[w][h]);
      half4_t pb;
      pb[0] = (_Float16)(ps[w][h][0] * r); pb[1] = (_Float16)(ps[w][h][1] * r);
      pb[2] = (_Float16)(ps[w][h][2] * r); pb[3] = (_Float16)(ps[w][h][3] * r);
      float4_t o0 = {0.f, 0.f, 0.f, 0.f};
      o0 = __builtin_amdgcn_mfma_f32_16x16x16f16(vt16[w][2 * h], pb, o0, 0, 0, 0);
      ao[w][2 * h] = pack4(o0);
      float4_t o1 = {0.f, 0.f, 0.f, 0.f};
      o1 = __builtin_amdgcn_mfma_f32_16x16x16f16(vt16[w][2 * h + 1], pb, o1, 0, 0, 0);
      ao[w][2 * h + 1] = pack4(o1);
    }
}

// GEMM3 + stores for a 2-window set
static __device__ __forceinline__ void gemm3_pair(
    const _Float16* woF, int lane, int g, const half4_t ao[2][6],
    const float* __restrict__ b_out, float* orow0, float* orow1) {
#pragma unroll
  for (int mt = 0; mt < 6; ++mt) {
    float4_t a0 = {0.f, 0.f, 0.f, 0.f};
    float4_t a1 = {0.f, 0.f, 0.f, 0.f};
#pragma unroll
    for (int kp = 0; kp < 3; ++kp) {
      half8_t wp = *(const half8_t*)&woF[((mt * 3 + kp) * 64 + lane) * 8];
      half4_t lo = __builtin_shufflevector(wp, wp, 0, 1, 2, 3);
      half4_t hi = __builtin_shufflevector(wp, wp, 4, 5, 6, 7);
      a0 = __builtin_amdgcn_mfma_f32_16x16x16f16(lo, ao[0][2 * kp],     a0, 0, 0, 0);
      a1 = __builtin_amdgcn_mfma_f32_16x16x16f16(lo, ao[1][2 * kp],     a1, 0, 0, 0);
      a0 = __builtin_amdgcn_mfma_f32_16x16x16f16(hi, ao[0][2 * kp + 1], a0, 0, 0, 0);
      a1 = __builtin_amdgcn_mfma_f32_16x16x16f16(hi, ao[1][2 * kp + 1], a1, 0, 0, 0);
    }
    float4_t bb = *(const float4_t*)&b_out[mt * 16 + g * 4];
    a0[0] += bb[0]; a0[1] += bb[1]; a0[2] += bb[2]; a0[3] += bb[3];
    a1[0] += bb[0]; a1[1] += bb[1]; a1[2] += bb[2]; a1[3] += bb[3];
    *(float4_t*)&orow0[mt * 16 + g * 4] = a0;
    *(float4_t*)&orow1[mt * 16 + g * 4] = a1;
  }
}

// Persistent 2-set r12: 512 thr, 8 waves, 2 windows/wave x 2 sets (32 win/blk,
// grid 784). Weights staged ONCE; set-1 x-loads issued between set-0 attention
// and GEMM3 so their HBM latency hides under set-0's GEMM3+stores (T14 split).
__global__ __launch_bounds__(512, 2)
void swin_fused(const float* __restrict__ x,
                const _Float16* __restrict__ wsh,
                const float* __restrict__ biasT,
                const float* __restrict__ b_out,
                float* __restrict__ out) {
  __shared__ _Float16 wL[36864];   // 73728 B: qkF | vB | woutB, frag-order
  const int tid  = threadIdx.x;
  const int wave = tid >> 6;
  const int lane = tid & 63;
  const int l15  = lane & 15;
  const int g    = lane >> 4;
  const int ty = l15 >> 2, tx = l15 & 3;

  const int gwin0 = blockIdx.x * 32 + wave * 2;        // set 0
  const int gwin1 = gwin0 + 16;                        // set 1

  // ---- set-0 x + bias loads (issued before staging: HBM latency overlaps)
  int pp0[2], qq0[2];
  float b00[2], b01[2], b02[2], b03[2];
  float4_t xa0[2][3], xb0[2][3];
  load_set(x, biasT, gwin0, ty, tx, g, l15, pp0, qq0, b00, b01, b02, b03, xa0, xb0);

  // ---- stage ALL weight frags once (4608 16B chunks = 9 iters x 512 thr)
  {
    const char* gs = (const char*)wsh;
    char* lb = (char*)wL;
#pragma unroll
    for (int k = 0; k < 9; ++k) {
      int cb = k * 512 + wave * 64;
      size_t off = (size_t)(cb + lane) * 16;
      gload_lds16(gs + off, lb + off);
    }
  }

  half8_t xf0[2][3];
  conv_set(xa0, xb0, xf0);

  __syncthreads();   // staging complete

  const _Float16* qkF = wL;
  const _Float16* vF  = wL + VB_OFF;
  const _Float16* woF = wL + WOUTB_OFF;

  // ---- set 0: GEMM1 + attention
  half4_t ao0[2][6];
  attn_pair(xf0, b00, b01, b02, b03, qkF, vF, lane, ao0);

  // ---- issue set-1 x + bias loads NOW (latency hides under set-0 GEMM3)
  int pp1[2], qq1[2];
  float b10[2], b11[2], b12[2], b13[2];
  float4_t xa1[2][3], xb1[2][3];
  load_set(x, biasT, gwin1, ty, tx, g, l15, pp1, qq1, b10, b11, b12, b13, xa1, xb1);

  // ---- set 0: GEMM3 + stores
  {
    const int batch = gwin0 / 784;
    float* o0 = out + (((size_t)batch * 112 + pp0[0]) * 112 + qq0[0]) * 96;
    float* o1 = out + (((size_t)batch * 112 + pp0[1]) * 112 + qq0[1]) * 96;
    gemm3_pair(woF, lane, g, ao0, b_out, o0, o1);
  }

  // ---- set 1: convert, compute, store
  half8_t xf1[2][3];
  conv_set(xa1, xb1, xf1);
  half4_t ao1[2][6];
  attn_pair(xf1, b10, b11, b12, b13, qkF, vF, lane, ao1);
  {
    const int batch = gwin1 / 784;
    float* o0 = out + (((size_t)batch * 112 + pp1[0]) * 112 + qq1[0]) * 96;
    float* o1 = out + (((size_t)batch * 112 + pp1[1]) * 112 + qq1[1]) * 96;
    gemm3_pair(woF, lane, g, ao1, b_out, o0, o1);
  }
}

extern "C" void kernel_launch(void* const* d_in, const int* in_sizes, int n_in,
                              void* d_out, int out_size, void* d_ws, size_t ws_size,
                              hipStream_t stream) {
  const float* x    = (const float*)d_in[0];
  const float* Wqkv = (const float*)d_in[1];
  const float* pos  = (const float*)d_in[2];
  const float* Wout = (const float*)d_in[3];
  const float* bout = (const float*)d_in[4];
  char* ws = (char*)d_ws;
  _Float16* wsh  = (_Float16*)ws;
  float* biasT = (float*)(ws + BIAST_OFF_B);

  prep_kernel<<<148, 256, 0, stream>>>(Wqkv, Wout, pos, wsh, biasT);
  swin_fused<<<784, 512, 0, stream>>>(x, wsh, biasT, bout, (float*)d_out);
}

// Round 18
// 119.791 us; speedup vs baseline: 2.2840x; 2.2840x over previous
//
#include <hip/hip_runtime.h>

typedef _Float16 half8_t __attribute__((ext_vector_type(8)));
typedef _Float16 half4_t __attribute__((ext_vector_type(4)));
typedef float    float4_t __attribute__((ext_vector_type(4)));

// ---------------- ws layout (f16 elements unless noted) ----------------
// [0, 18432)        qkF   frag-order q,k weights
// [18432, 27648)    vB    frag-order v-weights
// [27648, 36864)    woutB frag-order Wout (kt-pairs)
// [36864 f16 = 73728 B, 77824 B)  biasT f32 [4][16][16]
#define VB_OFF 18432
#define WOUTB_OFF 27648
#define BIAST_OFF_B 73728

__global__ void prep_kernel(const float* __restrict__ Wqkv,
                            const float* __restrict__ Wout,
                            const float* __restrict__ pos,
                            _Float16* __restrict__ wsh,
                            float* __restrict__ biasT) {
  int idx = blockIdx.x * 256 + threadIdx.x;
  if (idx < 18432) {
    int j = idx & 7, lane = (idx >> 3) & 63, fk = idx >> 9;   // fk in [0,36)
    int f = fk / 3, kt = fk % 3;
    int l15 = lane & 15, g = lane >> 4;
    int k = kt * 32 + g * 8 + j;
    int fo = f * 16 + l15;
    wsh[idx] = (_Float16)Wqkv[k * 288 + fo];
  } else if (idx < 27648) {
    int t = idx - VB_OFF;
    int j = t & 7, lane = (t >> 3) & 63, fk = t >> 9;         // fk in [0,18)
    int f6 = fk / 3, kt = fk % 3;
    int l15 = lane & 15, g = lane >> 4;
    int k = kt * 32 + g * 8 + j;
    int fo = 192 + f6 * 16 + l15;
    wsh[idx] = (_Float16)Wqkv[k * 288 + fo];
  } else if (idx < 36864) {
    int t = idx - WOUTB_OFF;
    int s = t & 7, lane = (t >> 3) & 63, fk = t >> 9;         // fk in [0,18)
    int mt = fk / 3, kp = fk % 3;
    int l15 = lane & 15, g = lane >> 4;
    int kt = kp * 2 + (s >> 2), j = s & 3;
    int k = kt * 16 + g * 4 + j;
    int fo = mt * 16 + l15;
    wsh[idx] = (_Float16)Wout[k * 96 + fo];
  } else if (idx < 36864 + 1024) {
    int t = idx - 36864;
    int m = t >> 8, j = (t >> 4) & 15, i = t & 15;            // [j][i] = bias[i][j]
    int xi = i >> 2, yi = i & 3, xj = j >> 2, yj = j & 3;
    float v = pos[(xj - xi + 3) * 7 + (yj - yi + 3)];         // key minus query
    if ((m & 1) && ((i >= 8) != (j >= 8))) v -= 1e9f;
    if ((m & 2) && ((yi >= 2) != (yj >= 2))) v -= 1e9f;
    biasT[t] = v;
  }
}

static __device__ __forceinline__ half4_t pack4(float4_t a) {
  half4_t h;
  h[0] = (_Float16)a[0]; h[1] = (_Float16)a[1];
  h[2] = (_Float16)a[2]; h[3] = (_Float16)a[3];
  return h;
}

static __device__ __forceinline__ void gload_lds16(const void* g, void* l) {
  __builtin_amdgcn_global_load_lds(
      (const __attribute__((address_space(1))) unsigned int*)g,
      (__attribute__((address_space(3))) unsigned int*)l, 16, 0, 0);
}

// issue x loads + bias loads for a 2-window pair (gwin = flat window idx incl batch)
static __device__ __forceinline__ void load_set(
    const float* __restrict__ x, const float* __restrict__ biasT,
    int gwin, int ty, int tx, int g, int l15,
    int* pp, int* qq, float* bb0, float* bb1, float* bb2, float* bb3,
    float4_t xa[2][3], float4_t xb[2][3]) {
  const int batch = gwin / 784;
  const int wid0  = gwin % 784;
#pragma unroll
  for (int w = 0; w < 2; ++w) {
    int wid = wid0 + w;
    int wrow = wid / 28, wcol = wid % 28;
    int p = wrow * 4 + ty + 2; if (p >= 112) p -= 112;
    int q = wcol * 4 + tx + 2; if (q >= 112) q -= 112;
    pp[w] = p; qq[w] = q;
    const float* xr = x + (((size_t)batch * 112 + p) * 112 + q) * 96 + g * 8;
#pragma unroll
    for (int kt = 0; kt < 3; ++kt) {
      xa[w][kt] = *(const float4_t*)(xr + kt * 32);
      xb[w][kt] = *(const float4_t*)(xr + kt * 32 + 4);
    }
    int var = (wrow == 27 ? 1 : 0) + (wcol == 27 ? 2 : 0);
    const float* bt = biasT + var * 256 + g * 64 + l15;   // [var][j=4g+r][i=l15]
    bb0[w] = bt[0]; bb1[w] = bt[16]; bb2[w] = bt[32]; bb3[w] = bt[48];
  }
}

static __device__ __forceinline__ void conv_set(const float4_t xa[2][3],
                                                const float4_t xb[2][3],
                                                half8_t xf[2][3]) {
#pragma unroll
  for (int w = 0; w < 2; ++w)
#pragma unroll
    for (int kt = 0; kt < 3; ++kt) {
      half8_t h;
      h[0] = (_Float16)xa[w][kt][0]; h[1] = (_Float16)xa[w][kt][1];
      h[2] = (_Float16)xa[w][kt][2]; h[3] = (_Float16)xa[w][kt][3];
      h[4] = (_Float16)xb[w][kt][0]; h[5] = (_Float16)xb[w][kt][1];
      h[6] = (_Float16)xb[w][kt][2]; h[7] = (_Float16)xb[w][kt][3];
      xf[w][kt] = h;
    }
}

// GEMM1 (qk + v) + attention for a 2-window pair -> ao[2][6]  (r12 dataflow)
static __device__ __forceinline__ void attn_pair(
    const half8_t xf[2][3], const float* bb0, const float* bb1,
    const float* bb2, const float* bb3,
    const _Float16* qkF, const _Float16* vF, int lane, half4_t ao[2][6]) {
  const float scale = 0.17677669529663687f;  // 32^-0.5
  half4_t qk16[2][12];
#pragma unroll
  for (int f = 0; f < 12; ++f) {
    half8_t w0 = *(const half8_t*)&qkF[((f * 3 + 0) * 64 + lane) * 8];
    half8_t w1 = *(const half8_t*)&qkF[((f * 3 + 1) * 64 + lane) * 8];
    half8_t w2 = *(const half8_t*)&qkF[((f * 3 + 2) * 64 + lane) * 8];
    float4_t a0 = {0.f, 0.f, 0.f, 0.f};
    float4_t a1 = {0.f, 0.f, 0.f, 0.f};
    a0 = __builtin_amdgcn_mfma_f32_16x16x32_f16(w0, xf[0][0], a0, 0, 0, 0);
    a1 = __builtin_amdgcn_mfma_f32_16x16x32_f16(w0, xf[1][0], a1, 0, 0, 0);
    a0 = __builtin_amdgcn_mfma_f32_16x16x32_f16(w1, xf[0][1], a0, 0, 0, 0);
    a1 = __builtin_amdgcn_mfma_f32_16x16x32_f16(w1, xf[1][1], a1, 0, 0, 0);
    a0 = __builtin_amdgcn_mfma_f32_16x16x32_f16(w2, xf[0][2], a0, 0, 0, 0);
    a1 = __builtin_amdgcn_mfma_f32_16x16x32_f16(w2, xf[1][2], a1, 0, 0, 0);
    qk16[0][f] = pack4(a0);
    qk16[1][f] = pack4(a1);
  }
  half4_t vt16[2][6];
#pragma unroll
  for (int f6 = 0; f6 < 6; ++f6) {
    half8_t vb0 = *(const half8_t*)&vF[((f6 * 3 + 0) * 64 + lane) * 8];
    half8_t vb1 = *(const half8_t*)&vF[((f6 * 3 + 1) * 64 + lane) * 8];
    half8_t vb2 = *(const half8_t*)&vF[((f6 * 3 + 2) * 64 + lane) * 8];
    float4_t a0 = {0.f, 0.f, 0.f, 0.f};
    float4_t a1 = {0.f, 0.f, 0.f, 0.f};
    a0 = __builtin_amdgcn_mfma_f32_16x16x32_f16(xf[0][0], vb0, a0, 0, 0, 0);
    a1 = __builtin_amdgcn_mfma_f32_16x16x32_f16(xf[1][0], vb0, a1, 0, 0, 0);
    a0 = __builtin_amdgcn_mfma_f32_16x16x32_f16(xf[0][1], vb1, a0, 0, 0, 0);
    a1 = __builtin_amdgcn_mfma_f32_16x16x32_f16(xf[1][1], vb1, a1, 0, 0, 0);
    a0 = __builtin_amdgcn_mfma_f32_16x16x32_f16(xf[0][2], vb2, a0, 0, 0, 0);
    a1 = __builtin_amdgcn_mfma_f32_16x16x32_f16(xf[1][2], vb2, a1, 0, 0, 0);
    vt16[0][f6] = pack4(a0);
    vt16[1][f6] = pack4(a1);
  }
  float ps[2][3][4], ss[2][3];
#pragma unroll
  for (int h = 0; h < 3; ++h)
#pragma unroll
    for (int w = 0; w < 2; ++w) {
      float4_t dd = {0.f, 0.f, 0.f, 0.f};
      dd = __builtin_amdgcn_mfma_f32_16x16x16f16(qk16[w][6 + 2 * h], qk16[w][2 * h],     dd, 0, 0, 0);
      dd = __builtin_amdgcn_mfma_f32_16x16x16f16(qk16[w][7 + 2 * h], qk16[w][2 * h + 1], dd, 0, 0, 0);
      ps[w][h][0] = __expf(fmaf(dd[0], scale, bb0[w]));
      ps[w][h][1] = __expf(fmaf(dd[1], scale, bb1[w]));
      ps[w][h][2] = __expf(fmaf(dd[2], scale, bb2[w]));
      ps[w][h][3] = __expf(fmaf(dd[3], scale, bb3[w]));
      ss[w][h] = (ps[w][h][0] + ps[w][h][1]) + (ps[w][h][2] + ps[w][h][3]);
    }
#pragma unroll
  for (int w = 0; w < 2; ++w)
#pragma unroll
    for (int h = 0; h < 3; ++h)
      ss[w][h] += __shfl_xor(ss[w][h], 16, 64);
#pragma unroll
  for (int w = 0; w < 2; ++w)
#pragma unroll
    for (int h = 0; h < 3; ++h)
      ss[w][h] += __shfl_xor(ss[w][h], 32, 64);
#pragma unroll
  for (int h = 0; h < 3; ++h)
#pragma unroll
    for (int w = 0; w < 2; ++w) {
      float r = __builtin_amdgcn_rcpf(ss[w][h]);
      half4_t pb;
      pb[0] = (_Float16)(ps[w][h][0] * r); pb[1] = (_Float16)(ps[w][h][1] * r);
      pb[2] = (_Float16)(ps[w][h][2] * r); pb[3] = (_Float16)(ps[w][h][3] * r);
      float4_t o0 = {0.f, 0.f, 0.f, 0.f};
      o0 = __builtin_amdgcn_mfma_f32_16x16x16f16(vt16[w][2 * h], pb, o0, 0, 0, 0);
      ao[w][2 * h] = pack4(o0);
      float4_t o1 = {0.f, 0.f, 0.f, 0.f};
      o1 = __builtin_amdgcn_mfma_f32_16x16x16f16(vt16[w][2 * h + 1], pb, o1, 0, 0, 0);
      ao[w][2 * h + 1] = pack4(o1);
    }
}

// GEMM3 + stores for a 2-window pair
static __device__ __forceinline__ void gemm3_pair(
    const _Float16* woF, int lane, int g, const half4_t ao[2][6],
    const float* __restrict__ b_out, float* orow0, float* orow1) {
#pragma unroll
  for (int mt = 0; mt < 6; ++mt) {
    float4_t a0 = {0.f, 0.f, 0.f, 0.f};
    float4_t a1 = {0.f, 0.f, 0.f, 0.f};
#pragma unroll
    for (int kp = 0; kp < 3; ++kp) {
      half8_t wp = *(const half8_t*)&woF[((mt * 3 + kp) * 64 + lane) * 8];
      half4_t lo = __builtin_shufflevector(wp, wp, 0, 1, 2, 3);
      half4_t hi = __builtin_shufflevector(wp, wp, 4, 5, 6, 7);
      a0 = __builtin_amdgcn_mfma_f32_16x16x16f16(lo, ao[0][2 * kp],     a0, 0, 0, 0);
      a1 = __builtin_amdgcn_mfma_f32_16x16x16f16(lo, ao[1][2 * kp],     a1, 0, 0, 0);
      a0 = __builtin_amdgcn_mfma_f32_16x16x16f16(hi, ao[0][2 * kp + 1], a0, 0, 0, 0);
      a1 = __builtin_amdgcn_mfma_f32_16x16x16f16(hi, ao[1][2 * kp + 1], a1, 0, 0, 0);
    }
    float4_t bb = *(const float4_t*)&b_out[mt * 16 + g * 4];
    a0[0] += bb[0]; a0[1] += bb[1]; a0[2] += bb[2]; a0[3] += bb[3];
    a1[0] += bb[0]; a1[1] += bb[1]; a1[2] += bb[2]; a1[3] += bb[3];
    *(float4_t*)&orow0[mt * 16 + g * 4] = a0;
    *(float4_t*)&orow1[mt * 16 + g * 4] = a1;
  }
}

// PERSISTENT r12: grid 256 (1 block/CU), 512 thr (8 waves, 2 win/wave).
// Weights staged ONCE per kernel; ONE barrier total; each wave loops over
// ~6 window-pairs (pi = gw + 2048*it) with next-pair x-loads issued BEFORE
// current compute (HBM latency hides under MFMA). Tail: wave 0 of each block
// takes pair 12288+blk (tail = 1 pair, spread over all CUs).
__global__ __launch_bounds__(512, 3)
void swin_fused(const float* __restrict__ x,
                const _Float16* __restrict__ wsh,
                const float* __restrict__ biasT,
                const float* __restrict__ b_out,
                float* __restrict__ out) {
  __shared__ _Float16 wL[36864];   // 73728 B: qkF | vB | woutB, frag-order
  const int tid  = threadIdx.x;
  const int wave = tid >> 6;
  const int lane = tid & 63;
  const int l15  = lane & 15;
  const int g    = lane >> 4;
  const int ty = l15 >> 2, tx = l15 & 3;

  const int gw = blockIdx.x * 8 + wave;   // 0..2047 global wave id

  // ---- prologue: first pair's x + bias loads (overlap with staging)
  int pp[2], qq[2];
  float bb0[2], bb1[2], bb2[2], bb3[2];
  float4_t xa[2][3], xb[2][3];
  int pi = gw;                             // pair index for it=0
  load_set(x, biasT, pi * 2, ty, tx, g, l15, pp, qq, bb0, bb1, bb2, bb3, xa, xb);

  // ---- stage ALL weight frags once (4608 16B chunks = 9 iters x 512 thr)
  {
    const char* gs = (const char*)wsh;
    char* lb = (char*)wL;
#pragma unroll
    for (int k = 0; k < 9; ++k) {
      int cb = k * 512 + wave * 64;
      size_t off = (size_t)(cb + lane) * 16;
      gload_lds16(gs + off, lb + off);
    }
  }

  half8_t xf[2][3];
  conv_set(xa, xb, xf);

  __syncthreads();   // the ONLY barrier: staging complete; LDS read-only after

  const _Float16* qkF = wL;
  const _Float16* vF  = wL + VB_OFF;
  const _Float16* woF = wL + WOUTB_OFF;

  for (int it = 0; it < 7; ++it) {
    const bool vc = (it < 6) || (wave == 0);
    const int pin = (it < 5) ? (pi + 2048) : (12288 + (int)blockIdx.x);
    const bool vn = (it < 5) || (it == 5 && wave == 0);

    // issue next pair's loads NOW (latency hides under current compute)
    int ppn[2], qqn[2];
    float nb0[2], nb1[2], nb2[2], nb3[2];
    if (vn)
      load_set(x, biasT, pin * 2, ty, tx, g, l15, ppn, qqn, nb0, nb1, nb2, nb3, xa, xb);

    if (vc) {
      half4_t ao[2][6];
      attn_pair(xf, bb0, bb1, bb2, bb3, qkF, vF, lane, ao);
      const int batch = (pi * 2) / 784;
      float* o0 = out + (((size_t)batch * 112 + pp[0]) * 112 + qq[0]) * 96;
      float* o1 = out + (((size_t)batch * 112 + pp[1]) * 112 + qq[1]) * 96;
      gemm3_pair(woF, lane, g, ao, b_out, o0, o1);
    }

    if (vn) {
      conv_set(xa, xb, xf);   // waits on the in-flight loads (had full compute to land)
      pp[0] = ppn[0]; pp[1] = ppn[1]; qq[0] = qqn[0]; qq[1] = qqn[1];
      bb0[0] = nb0[0]; bb0[1] = nb0[1]; bb1[0] = nb1[0]; bb1[1] = nb1[1];
      bb2[0] = nb2[0]; bb2[1] = nb2[1]; bb3[0] = nb3[0]; bb3[1] = nb3[1];
    }
    pi = pin;
  }
}

extern "C" void kernel_launch(void* const* d_in, const int* in_sizes, int n_in,
                              void* d_out, int out_size, void* d_ws, size_t ws_size,
                              hipStream_t stream) {
  const float* x    = (const float*)d_in[0];
  const float* Wqkv = (const float*)d_in[1];
  const float* pos  = (const float*)d_in[2];
  const float* Wout = (const float*)d_in[3];
  const float* bout = (const float*)d_in[4];
  char* ws = (char*)d_ws;
  _Float16* wsh  = (_Float16*)ws;
  float* biasT = (float*)(ws + BIAST_OFF_B);

  prep_kernel<<<148, 256, 0, stream>>>(Wqkv, Wout, pos, wsh, biasT);
  swin_fused<<<256, 512, 0, stream>>>(x, wsh, biasT, bout, (float*)d_out);
}

// Round 19
// 98.650 us; speedup vs baseline: 2.7734x; 1.2143x over previous
//
#include <hip/hip_runtime.h>

typedef _Float16 half8_t __attribute__((ext_vector_type(8)));
typedef _Float16 half4_t __attribute__((ext_vector_type(4)));
typedef float    float4_t __attribute__((ext_vector_type(4)));

// ---------------- ws layout (f16 elements unless noted) ----------------
// [0, 18432)        qkF   frag-order q,k weights
// [18432, 27648)    vB    frag-order v-weights
// [27648, 36864)    woutB frag-order Wout (kt-pairs)   [stays in L2, not LDS]
// [36864 f16 = 73728 B, 77824 B)  biasT f32 [4][16][16]
#define VB_OFF 18432
#define WOUTB_OFF 27648
#define BIAST_OFF_B 73728

__global__ void prep_kernel(const float* __restrict__ Wqkv,
                            const float* __restrict__ Wout,
                            const float* __restrict__ pos,
                            _Float16* __restrict__ wsh,
                            float* __restrict__ biasT) {
  int idx = blockIdx.x * 256 + threadIdx.x;
  if (idx < 18432) {
    int j = idx & 7, lane = (idx >> 3) & 63, fk = idx >> 9;   // fk in [0,36)
    int f = fk / 3, kt = fk % 3;
    int l15 = lane & 15, g = lane >> 4;
    int k = kt * 32 + g * 8 + j;
    int fo = f * 16 + l15;
    wsh[idx] = (_Float16)Wqkv[k * 288 + fo];
  } else if (idx < 27648) {
    int t = idx - VB_OFF;
    int j = t & 7, lane = (t >> 3) & 63, fk = t >> 9;         // fk in [0,18)
    int f6 = fk / 3, kt = fk % 3;
    int l15 = lane & 15, g = lane >> 4;
    int k = kt * 32 + g * 8 + j;
    int fo = 192 + f6 * 16 + l15;
    wsh[idx] = (_Float16)Wqkv[k * 288 + fo];
  } else if (idx < 36864) {
    int t = idx - WOUTB_OFF;
    int s = t & 7, lane = (t >> 3) & 63, fk = t >> 9;         // fk in [0,18)
    int mt = fk / 3, kp = fk % 3;
    int l15 = lane & 15, g = lane >> 4;
    int kt = kp * 2 + (s >> 2), j = s & 3;
    int k = kt * 16 + g * 4 + j;
    int fo = mt * 16 + l15;
    wsh[idx] = (_Float16)Wout[k * 96 + fo];
  } else if (idx < 36864 + 1024) {
    int t = idx - 36864;
    int m = t >> 8, j = (t >> 4) & 15, i = t & 15;            // [j][i] = bias[i][j]
    int xi = i >> 2, yi = i & 3, xj = j >> 2, yj = j & 3;
    float v = pos[(xj - xi + 3) * 7 + (yj - yi + 3)];         // key minus query
    if ((m & 1) && ((i >= 8) != (j >= 8))) v -= 1e9f;
    if ((m & 2) && ((yi >= 2) != (yj >= 2))) v -= 1e9f;
    biasT[t] = v;
  }
}

static __device__ __forceinline__ half4_t pack4(float4_t a) {
  half4_t h;
  h[0] = (_Float16)a[0]; h[1] = (_Float16)a[1];
  h[2] = (_Float16)a[2]; h[3] = (_Float16)a[3];
  return h;
}

static __device__ __forceinline__ void gload_lds16(const void* g, void* l) {
  __builtin_amdgcn_global_load_lds(
      (const __attribute__((address_space(1))) unsigned int*)g,
      (__attribute__((address_space(3))) unsigned int*)l, 16, 0, 0);
}

// r12 dataflow with (1) qkF+vB-only LDS (55296 B -> 2 resident blocks/CU,
// r13-measured) while GEMM3 preloads Wout frags from L2-resident global at the
// SAME liveness point r12 used (qk16/vt16 dead there -> zero added pressure),
// and (2) defer-normalized softmax: PV consumes unnormalized exp (f16-safe,
// logits << 11), 1/sum applied to PV output -> shuffle-reduce overlaps PV MFMA.
__global__ __launch_bounds__(512, 4)
void swin_fused(const float* __restrict__ x,
                const _Float16* __restrict__ wsh,
                const float* __restrict__ biasT,
                const float* __restrict__ b_out,
                float* __restrict__ out) {
  __shared__ _Float16 wL[27648];   // 55296 B: qkF | vB, frag-order
  const int tid  = threadIdx.x;
  const int wave = tid >> 6;
  const int lane = tid & 63;
  const int l15  = lane & 15;
  const int g    = lane >> 4;
  const int ty = l15 >> 2, tx = l15 & 3;

  const int blk   = blockIdx.x;
  const int batch = blk / 49;
  const int wbase = (blk % 49) * 16 + wave * 2;   // this wave's 2 windows

  // per-window token positions (cyclic shift folded in; reused for stores)
  int pp[2], qq[2];
#pragma unroll
  for (int w = 0; w < 2; ++w) {
    int wid = wbase + w;
    int wrow = wid / 28, wcol = wid % 28;
    int p = wrow * 4 + ty + 2; if (p >= 112) p -= 112;
    int q = wcol * 4 + tx + 2; if (q >= 112) q -= 112;
    pp[w] = p; qq[w] = q;
  }

  // ---- issue x loads
  float4_t xa[2][3], xb[2][3];
#pragma unroll
  for (int w = 0; w < 2; ++w) {
    const float* xr = x + (((size_t)batch * 112 + pp[w]) * 112 + qq[w]) * 96 + g * 8;
#pragma unroll
    for (int kt = 0; kt < 3; ++kt) {
      xa[w][kt] = *(const float4_t*)(xr + kt * 32);
      xb[w][kt] = *(const float4_t*)(xr + kt * 32 + 4);
    }
  }

  // ---- async stage qk+v frags (3456 16B chunks = 7 iters x 512 thr, guarded)
  {
    const char* gs = (const char*)wsh;
    char* lb = (char*)wL;
#pragma unroll
    for (int k = 0; k < 7; ++k) {
      int cb = k * 512 + wave * 64;          // wave-uniform chunk base
      if (cb < 3456) {
        size_t off = (size_t)(cb + lane) * 16;
        gload_lds16(gs + off, lb + off);
      }
    }
  }

  // ---- per-window bias values
  float bb0[2], bb1[2], bb2[2], bb3[2];
#pragma unroll
  for (int w = 0; w < 2; ++w) {
    int wid = wbase + w;
    int var = ((wid / 28) == 27 ? 1 : 0) + ((wid % 28) == 27 ? 2 : 0);
    const float* bt = biasT + var * 256 + g * 64 + l15;   // [var][j=4g+r][i=l15]
    bb0[w] = bt[0]; bb1[w] = bt[16]; bb2[w] = bt[32]; bb3[w] = bt[48];
  }

  // ---- convert x to f16 fragments
  half8_t xf[2][3];
#pragma unroll
  for (int w = 0; w < 2; ++w)
#pragma unroll
    for (int kt = 0; kt < 3; ++kt) {
      half8_t h;
      h[0] = (_Float16)xa[w][kt][0]; h[1] = (_Float16)xa[w][kt][1];
      h[2] = (_Float16)xa[w][kt][2]; h[3] = (_Float16)xa[w][kt][3];
      h[4] = (_Float16)xb[w][kt][0]; h[5] = (_Float16)xb[w][kt][1];
      h[6] = (_Float16)xb[w][kt][2]; h[7] = (_Float16)xb[w][kt][3];
      xf[w][kt] = h;
    }

  __syncthreads();   // staging complete (barrier drains vmcnt incl. global_load_lds)

  const _Float16* qkF = wL;
  const _Float16* vF  = wL + VB_OFF;
  const _Float16* woF = wsh + WOUTB_OFF;   // L2-resident global (9.2 KB, hot)
  const float scale = 0.17677669529663687f;  // 32^-0.5

  // ---- GEMM1 qk tiles, interleaved: one frag load feeds BOTH windows
  half4_t qk16[2][12];
#pragma unroll
  for (int f = 0; f < 12; ++f) {
    half8_t w0 = *(const half8_t*)&qkF[((f * 3 + 0) * 64 + lane) * 8];
    half8_t w1 = *(const half8_t*)&qkF[((f * 3 + 1) * 64 + lane) * 8];
    half8_t w2 = *(const half8_t*)&qkF[((f * 3 + 2) * 64 + lane) * 8];
    float4_t a0 = {0.f, 0.f, 0.f, 0.f};
    float4_t a1 = {0.f, 0.f, 0.f, 0.f};
    a0 = __builtin_amdgcn_mfma_f32_16x16x32_f16(w0, xf[0][0], a0, 0, 0, 0);
    a1 = __builtin_amdgcn_mfma_f32_16x16x32_f16(w0, xf[1][0], a1, 0, 0, 0);
    a0 = __builtin_amdgcn_mfma_f32_16x16x32_f16(w1, xf[0][1], a0, 0, 0, 0);
    a1 = __builtin_amdgcn_mfma_f32_16x16x32_f16(w1, xf[1][1], a1, 0, 0, 0);
    a0 = __builtin_amdgcn_mfma_f32_16x16x32_f16(w2, xf[0][2], a0, 0, 0, 0);
    a1 = __builtin_amdgcn_mfma_f32_16x16x32_f16(w2, xf[1][2], a1, 0, 0, 0);
    qk16[0][f] = pack4(a0);
    qk16[1][f] = pack4(a1);
  }

  // ---- GEMM1 v tiles, interleaved
  half4_t vt16[2][6];
#pragma unroll
  for (int f6 = 0; f6 < 6; ++f6) {
    half8_t vb0 = *(const half8_t*)&vF[((f6 * 3 + 0) * 64 + lane) * 8];
    half8_t vb1 = *(const half8_t*)&vF[((f6 * 3 + 1) * 64 + lane) * 8];
    half8_t vb2 = *(const half8_t*)&vF[((f6 * 3 + 2) * 64 + lane) * 8];
    float4_t a0 = {0.f, 0.f, 0.f, 0.f};
    float4_t a1 = {0.f, 0.f, 0.f, 0.f};
    a0 = __builtin_amdgcn_mfma_f32_16x16x32_f16(xf[0][0], vb0, a0, 0, 0, 0);
    a1 = __builtin_amdgcn_mfma_f32_16x16x32_f16(xf[1][0], vb0, a1, 0, 0, 0);
    a0 = __builtin_amdgcn_mfma_f32_16x16x32_f16(xf[0][1], vb1, a0, 0, 0, 0);
    a1 = __builtin_amdgcn_mfma_f32_16x16x32_f16(xf[1][1], vb1, a1, 0, 0, 0);
    a0 = __builtin_amdgcn_mfma_f32_16x16x32_f16(xf[0][2], vb2, a0, 0, 0, 0);
    a1 = __builtin_amdgcn_mfma_f32_16x16x32_f16(xf[1][2], vb2, a1, 0, 0, 0);
    vt16[0][f6] = pack4(a0);
    vt16[1][f6] = pack4(a1);
  }

  // ---- attention, interleaved: QK^T + exp (no max-subtract), DEFER-NORM:
  // PV consumes unnormalized exp; 1/sum applied to PV output, so the
  // cross-lane sum reduce overlaps PV MFMA issue.
  float ps[2][3][4], ss[2][3];
#pragma unroll
  for (int h = 0; h < 3; ++h)
#pragma unroll
    for (int w = 0; w < 2; ++w) {
      float4_t dd = {0.f, 0.f, 0.f, 0.f};
      dd = __builtin_amdgcn_mfma_f32_16x16x16f16(qk16[w][6 + 2 * h], qk16[w][2 * h],     dd, 0, 0, 0);
      dd = __builtin_amdgcn_mfma_f32_16x16x16f16(qk16[w][7 + 2 * h], qk16[w][2 * h + 1], dd, 0, 0, 0);
      ps[w][h][0] = __expf(fmaf(dd[0], scale, bb0[w]));
      ps[w][h][1] = __expf(fmaf(dd[1], scale, bb1[w]));
      ps[w][h][2] = __expf(fmaf(dd[2], scale, bb2[w]));
      ps[w][h][3] = __expf(fmaf(dd[3], scale, bb3[w]));
      ss[w][h] = (ps[w][h][0] + ps[w][h][1]) + (ps[w][h][2] + ps[w][h][3]);
    }
#pragma unroll
  for (int w = 0; w < 2; ++w)
#pragma unroll
    for (int h = 0; h < 3; ++h)
      ss[w][h] += __shfl_xor(ss[w][h], 16, 64);
#pragma unroll
  for (int w = 0; w < 2; ++w)
#pragma unroll
    for (int h = 0; h < 3; ++h)
      ss[w][h] += __shfl_xor(ss[w][h], 32, 64);

  half4_t ao[2][6];
#pragma unroll
  for (int h = 0; h < 3; ++h)
#pragma unroll
    for (int w = 0; w < 2; ++w) {
      half4_t pb;   // P^T unnormalized (col=query l15, k=key 4g+r); <= e^~5, f16-safe
      pb[0] = (_Float16)ps[w][h][0]; pb[1] = (_Float16)ps[w][h][1];
      pb[2] = (_Float16)ps[w][h][2]; pb[3] = (_Float16)ps[w][h][3];
      float4_t o0 = {0.f, 0.f, 0.f, 0.f};
      o0 = __builtin_amdgcn_mfma_f32_16x16x16f16(vt16[w][2 * h], pb, o0, 0, 0, 0);
      float4_t o1 = {0.f, 0.f, 0.f, 0.f};
      o1 = __builtin_amdgcn_mfma_f32_16x16x16f16(vt16[w][2 * h + 1], pb, o1, 0, 0, 0);
      float r = __builtin_amdgcn_rcpf(ss[w][h]);   // per-query (lane) scale
      o0[0] *= r; o0[1] *= r; o0[2] *= r; o0[3] *= r;
      o1[0] *= r; o1[1] *= r; o1[2] *= r; o1[3] *= r;
      ao[w][2 * h] = pack4(o0);
      ao[w][2 * h + 1] = pack4(o1);
    }

  // ---- GEMM3 interleaved; preload ALL 18 Wout frag-pairs from L2 global
  // (same liveness point as r12 -- qk16/vt16 dead, regs free)
  half8_t wo[18];
#pragma unroll
  for (int i = 0; i < 18; ++i)
    wo[i] = *(const half8_t*)&woF[(i * 64 + lane) * 8];

  float* orow0 = out + (((size_t)batch * 112 + pp[0]) * 112 + qq[0]) * 96;
  float* orow1 = out + (((size_t)batch * 112 + pp[1]) * 112 + qq[1]) * 96;
#pragma unroll
  for (int mt = 0; mt < 6; ++mt) {
    float4_t a0 = {0.f, 0.f, 0.f, 0.f};
    float4_t a1 = {0.f, 0.f, 0.f, 0.f};
#pragma unroll
    for (int kp = 0; kp < 3; ++kp) {
      half8_t wp = wo[mt * 3 + kp];
      half4_t lo = __builtin_shufflevector(wp, wp, 0, 1, 2, 3);
      half4_t hi = __builtin_shufflevector(wp, wp, 4, 5, 6, 7);
      a0 = __builtin_amdgcn_mfma_f32_16x16x16f16(lo, ao[0][2 * kp],     a0, 0, 0, 0);
      a1 = __builtin_amdgcn_mfma_f32_16x16x16f16(lo, ao[1][2 * kp],     a1, 0, 0, 0);
      a0 = __builtin_amdgcn_mfma_f32_16x16x16f16(hi, ao[0][2 * kp + 1], a0, 0, 0, 0);
      a1 = __builtin_amdgcn_mfma_f32_16x16x16f16(hi, ao[1][2 * kp + 1], a1, 0, 0, 0);
    }
    float4_t bb = *(const float4_t*)&b_out[mt * 16 + g * 4];
    a0[0] += bb[0]; a0[1] += bb[1]; a0[2] += bb[2]; a0[3] += bb[3];
    a1[0] += bb[0]; a1[1] += bb[1]; a1[2] += bb[2]; a1[3] += bb[3];
    *(float4_t*)&orow0[mt * 16 + g * 4] = a0;
    *(float4_t*)&orow1[mt * 16 + g * 4] = a1;
  }
}

extern "C" void kernel_launch(void* const* d_in, const int* in_sizes, int n_in,
                              void* d_out, int out_size, void* d_ws, size_t ws_size,
                              hipStream_t stream) {
  const float* x    = (const float*)d_in[0];
  const float* Wqkv = (const float*)d_in[1];
  const float* pos  = (const float*)d_in[2];
  const float* Wout = (const float*)d_in[3];
  const float* bout = (const float*)d_in[4];
  char* ws = (char*)d_ws;
  _Float16* wsh  = (_Float16*)ws;
  float* biasT = (float*)(ws + BIAST_OFF_B);

  prep_kernel<<<148, 256, 0, stream>>>(Wqkv, Wout, pos, wsh, biasT);
  swin_fused<<<1568, 512, 0, stream>>>(x, wsh, biasT, bout, (float*)d_out);
}